// Round 8
// baseline (629.470 us; speedup 1.0000x reference)
//
#include <hip/hip_runtime.h>

#define NN 100000
#define NE 1600000
#define DF 128
#define TS 136    // LDS row stride in u16: 272 B -> 2-way (free) bank aliasing on frag reads
#define NCB 391   // coarse buckets: dst>>8, 256 nodes each
#define NWA 256   // pass-A workgroups (wg-private regions scale with this)
#define SZA 6250  // edges per pass-A stripe (NE/NWA)
#define NH (NCB * NWA)  // 100096
#define CHK 98    // scanH chunk per thread (ceil NH/1024)
#define CAPB 6144 // pass-B LDS seg capacity (mean 4092 edges/cb, +32 sigma)

typedef unsigned int uint32;
typedef unsigned short u16;
typedef _Float16 f16;
typedef f16 f16x8 __attribute__((ext_vector_type(8)));
typedef f16 f16x2 __attribute__((ext_vector_type(2)));
typedef float f32x4 __attribute__((ext_vector_type(4)));

// ---- fp16 helpers ----
__device__ __forceinline__ float2 up2(uint32 u) {
    union { uint32 u; f16x2 h; } v; v.u = u;
    return make_float2((float)v.h.x, (float)v.h.y);
}
__device__ __forceinline__ uint32 pk2(float a, float b) {
    union { f16x2 h; uint32 u; } v;
    v.h.x = (f16)a; v.h.y = (f16)b;
    return v.u;
}
__device__ __forceinline__ u16 f2h(float a) {
    union { f16 h; u16 u; } v; v.h = (f16)a; return v.u;
}
__device__ __forceinline__ float h2f(u16 a) {
    union { u16 u; f16 h; } v; v.u = a; return (float)v.h;
}

// ================= CSR build: two-pass counting sort =================
// Pass A partitions edges by coarse key (dst>>8) into ebuf with
// WORKGROUP-PRIVATE regions (no global atomics; each 64B line dirtied by
// ~one wg -> minimal writeback amplification, independent of wg->XCD map).
// Pass B sorts each coarse bucket fully in LDS -> coalesced col + rowptr.

__global__ __launch_bounds__(256) void histA(const int* __restrict__ dst,
                                             int* __restrict__ H) {
    __shared__ int lh[NCB];
    int w = blockIdx.x, t = threadIdx.x;
    for (int i = t; i < NCB; i += 256) lh[i] = 0;
    __syncthreads();
    int e0 = w * SZA, e1 = min(e0 + SZA, NE);
    for (int e = e0 + t; e < e1; e += 256) atomicAdd(&lh[dst[e] >> 8], 1);
    __syncthreads();
    for (int i = t; i < NCB; i += 256) H[i * NWA + w] = lh[i];
}

// exclusive scan of H[NH] -> O[NH], O[NH]=NE; also rowptr[NN]=NE.
// Two-phase per thread (sum, then re-read & emit) to avoid big local arrays.
__global__ __launch_bounds__(1024) void scanH(const int* __restrict__ H,
                                              int* __restrict__ O,
                                              int* __restrict__ rowptr) {
    __shared__ int sm[1024];
    int t = threadIdx.x;
    int b0 = t * CHK;
    int s = 0;
    for (int i = 0; i < CHK; ++i) {
        int b = b0 + i;
        if (b < NH) s += H[b];
    }
    sm[t] = s;
    __syncthreads();
    for (int off = 1; off < 1024; off <<= 1) {
        int x = (t >= off) ? sm[t - off] : 0;
        __syncthreads();
        sm[t] += x;
        __syncthreads();
    }
    int run = (t > 0) ? sm[t - 1] : 0;
    for (int i = 0; i < CHK; ++i) {
        int b = b0 + i;
        if (b < NH) {
            O[b] = run;
            run += H[b];
        }
    }
    if (t == 1023) {
        O[NH] = sm[1023];
        rowptr[NN] = sm[1023];
    }
}

__global__ __launch_bounds__(1024) void passA(const int* __restrict__ src,
                                              const int* __restrict__ dst,
                                              const int* __restrict__ O,
                                              uint32* __restrict__ ebuf) {
    __shared__ int cur[NCB];
    int w = blockIdx.x, t = threadIdx.x;
    for (int i = t; i < NCB; i += 1024) cur[i] = O[i * NWA + w];
    __syncthreads();
    int e0 = w * SZA, e1 = min(e0 + SZA, NE);
    for (int e = e0 + t; e < e1; e += 1024) {
        int d = dst[e];
        int cb = d >> 8;
        int p = atomicAdd(&cur[cb], 1);  // LDS atomic; region private to this wg
        ebuf[p] = ((uint32)src[e] << 8) | (uint32)(d & 255);
    }
}

__global__ __launch_bounds__(256) void passB(const uint32* __restrict__ ebuf,
                                             const int* __restrict__ O,
                                             int* __restrict__ rowptr,
                                             int* __restrict__ col) {
    __shared__ int hist[256], start[256], cur[256];
    __shared__ int seg[CAPB];
    int cb = blockIdx.x, t = threadIdx.x;
    int base = O[cb * NWA], end = O[(cb + 1) * NWA];  // cb=NCB-1 reads O[NH]=NE
    int m = end - base;
    hist[t] = 0;
    __syncthreads();
    for (int i = t; i < m; i += 256) atomicAdd(&hist[ebuf[base + i] & 255], 1);
    __syncthreads();
    int v = hist[t];
    cur[t] = v;
    __syncthreads();
    for (int off = 1; off < 256; off <<= 1) {
        int x = (t >= off) ? cur[t - off] : 0;
        __syncthreads();
        cur[t] += x;
        __syncthreads();
    }
    start[t] = cur[t] - v;
    __syncthreads();
    int node = cb * 256 + t;
    if (node < NN) rowptr[node] = base + start[t];
    cur[t] = start[t];
    __syncthreads();
    if (m <= CAPB) {  // fast path: sort into LDS, stream out coalesced
        for (int i = t; i < m; i += 256) {
            uint32 u = ebuf[base + i];
            int p = atomicAdd(&cur[u & 255], 1);
            seg[p] = (int)(u >> 8);
        }
        __syncthreads();
        for (int i = t; i < m; i += 256) col[base + i] = seg[i];
    } else {  // correctness fallback
        for (int i = t; i < m; i += 256) {
            uint32 u = ebuf[base + i];
            int p = atomicAdd(&cur[u & 255], 1);
            col[base + p] = (int)(u >> 8);
        }
    }
}

// ======= weight prep, all 6 matrices in one launch: fp32 [k][n] -> fp16 [n][k]
// WB layout: [0)=Ws0^T [1)=Wn0^T [2)=Ws1^T [3)=Wn1^T (16384 each);
// W2 block at 4*16384: rows 0-63 Ws2^T, rows 64-127 Wn2^T (each n*128+k).
__global__ void prep_all(const float* __restrict__ Ws0, const float* __restrict__ Wn0,
                         const float* __restrict__ Ws1, const float* __restrict__ Wn1,
                         const float* __restrict__ Ws2, const float* __restrict__ Wn2,
                         u16* __restrict__ WB) {
    int t = blockIdx.x * 256 + threadIdx.x;  // 0 .. 81919
    if (t < 65536) {
        int m = t >> 14;           // 0..3
        int local = t & 16383;
        int k = local >> 7, n = local & 127;
        const float* W = (m == 0) ? Ws0 : (m == 1) ? Wn0 : (m == 2) ? Ws1 : Wn1;
        WB[m * 16384 + n * 128 + k] = f2h(W[k * 128 + n]);
    } else {
        int local = t - 65536;     // 0 .. 16383
        int half = local >> 13;    // 0 = Ws2, 1 = Wn2
        int idx = local & 8191;
        int k = idx >> 6, n = idx & 63;
        const float* W = half ? Wn2 : Ws2;
        WB[4 * 16384 + (n + half * 64) * 128 + k] = f2h(W[k * 64 + n]);
    }
}

// ================= x -> fp16 =================
__global__ void cvt_f16(const float* __restrict__ x, uint2* __restrict__ xh) {
    int t = blockIdx.x * 256 + threadIdx.x;
    if (t < NN * DF / 4) {
        float4 v = ((const float4*)x)[t];
        uint2 o;
        o.x = pk2(v.x, v.y);
        o.y = pk2(v.z, v.w);
        xh[t] = o;
    }
}

// ================= gather mean, fp16 in/out, width 128 =================
__global__ __launch_bounds__(256) void gather_f16(const uint32* __restrict__ hb,
                                                  const int* __restrict__ rowptr,
                                                  const int* __restrict__ col,
                                                  uint32* __restrict__ mean) {
    int node = blockIdx.x * 4 + (threadIdx.x >> 6);
    int lane = threadIdx.x & 63;
    int s = rowptr[node], e = rowptr[node + 1];
    float sx = 0.f, sy = 0.f;
    int j = s;
    for (; j + 3 < e; j += 4) {
        int n0 = col[j], n1 = col[j + 1], n2 = col[j + 2], n3 = col[j + 3];
        uint32 u0 = hb[(size_t)n0 * 64 + lane];
        uint32 u1 = hb[(size_t)n1 * 64 + lane];
        uint32 u2 = hb[(size_t)n2 * 64 + lane];
        uint32 u3 = hb[(size_t)n3 * 64 + lane];
        float2 a = up2(u0), b = up2(u1), c = up2(u2), d = up2(u3);
        sx += a.x + b.x + c.x + d.x;
        sy += a.y + b.y + c.y + d.y;
    }
    for (; j < e; ++j) {
        float2 a = up2(hb[(size_t)col[j] * 64 + lane]);
        sx += a.x;
        sy += a.y;
    }
    float invd = 1.f / fmaxf((float)(e - s), 1.f);
    mean[(size_t)node * 64 + lane] = pk2(sx * invd, sy * invd);
}

// ================= gather mean-add, fp16 in, width 64, into fp32 out =========
__global__ __launch_bounds__(256) void gather_add_f16(const u16* __restrict__ gb,
                                                      const int* __restrict__ rowptr,
                                                      const int* __restrict__ col,
                                                      float* __restrict__ out) {
    int node = blockIdx.x * 4 + (threadIdx.x >> 6);
    int lane = threadIdx.x & 63;
    int s = rowptr[node], e = rowptr[node + 1];
    float acc = 0.f;
    int j = s;
    for (; j + 3 < e; j += 4) {
        int n0 = col[j], n1 = col[j + 1], n2 = col[j + 2], n3 = col[j + 3];
        acc += h2f(gb[(size_t)n0 * 64 + lane]) + h2f(gb[(size_t)n1 * 64 + lane]) +
               h2f(gb[(size_t)n2 * 64 + lane]) + h2f(gb[(size_t)n3 * 64 + lane]);
    }
    for (; j < e; ++j) acc += h2f(gb[(size_t)col[j] * 64 + lane]);
    float invd = 1.f / fmaxf((float)(e - s), 1.f);
    out[(size_t)node * 64 + lane] += acc * invd;
}

// ================= MFMA GEMM building blocks (fp16) ======
__device__ __forceinline__ void stage_a(u16* sm, const u16* g, int row0, int tid) {
#pragma unroll
    for (int i = 0; i < 8; ++i) {
        int idx = i * 256 + tid;
        int r = idx >> 4, c = (idx & 15) * 8;
        uint4 v = make_uint4(0, 0, 0, 0);
        int gr = row0 + r;
        if (gr < NN) v = *(const uint4*)(g + (size_t)gr * DF + c);
        *(uint4*)(sm + r * TS + c) = v;
    }
}

__device__ __forceinline__ void stage_w(u16* sm, const u16* wt, int nbase, int tid) {
#pragma unroll
    for (int i = 0; i < 4; ++i) {
        int idx = i * 256 + tid;
        int r = idx >> 4, c = (idx & 15) * 8;
        *(uint4*)(sm + r * TS + c) = *(const uint4*)(wt + (size_t)(nbase + r) * 128 + c);
    }
}

__device__ __forceinline__ f16x8 frag(const u16* sm, int row, int lane, int kc) {
    return *(const f16x8*)(sm + (row + (lane & 15)) * TS + kc * 32 + (lane >> 4) * 8);
}

__device__ __forceinline__ void mfma4(const u16* As, const u16* Bs, int wrow, int lane,
                                      f32x4 acc[2][8], int ab) {
    f16x8 a[2][4];
#pragma unroll
    for (int rt = 0; rt < 2; ++rt)
#pragma unroll
        for (int kc = 0; kc < 4; ++kc) a[rt][kc] = frag(As, wrow + rt * 16, lane, kc);
#pragma unroll
    for (int n = 0; n < 4; ++n) {
#pragma unroll
        for (int kc = 0; kc < 4; ++kc) {
            f16x8 b = frag(Bs, n * 16, lane, kc);
            acc[0][ab + n] = __builtin_amdgcn_mfma_f32_16x16x32_f16(a[0][kc], b, acc[0][ab + n], 0, 0, 0);
            acc[1][ab + n] = __builtin_amdgcn_mfma_f32_16x16x32_f16(a[1][kc], b, acc[1][ab + n], 0, 0, 0);
        }
    }
}

#define SW(WT, NB) { __syncthreads(); stage_w(Bs, WT, NB, tid); __syncthreads(); }

// ---- fused SAGE layer (DO=128): OutH = fp16(relu(H@Ws + M@Wn + b)), in-place safe
__global__ __launch_bounds__(256) void gemm_sage_f16(
    const u16* H, const u16* M,
    const u16* __restrict__ Ws, const u16* __restrict__ Wn,
    const float* __restrict__ bias, u16* OutH) {
    __shared__ u16 As[128 * TS];
    __shared__ u16 Bs[64 * TS];
    const int tid = threadIdx.x;
    const int lane = tid & 63;
    const int wrow = (tid >> 6) * 32;
    const int row0 = blockIdx.x * 128;

    f32x4 acc[2][8];
#pragma unroll
    for (int rt = 0; rt < 2; ++rt)
#pragma unroll
        for (int n = 0; n < 8; ++n) acc[rt][n] = {0.f, 0.f, 0.f, 0.f};

    stage_a(As, H, row0, tid);
    stage_w(Bs, Ws, 0, tid);
    __syncthreads();
    mfma4(As, Bs, wrow, lane, acc, 0);
    SW(Ws, 64); mfma4(As, Bs, wrow, lane, acc, 4);
    __syncthreads();
    stage_a(As, M, row0, tid);
    stage_w(Bs, Wn, 0, tid);
    __syncthreads();
    mfma4(As, Bs, wrow, lane, acc, 0);
    SW(Wn, 64); mfma4(As, Bs, wrow, lane, acc, 4);

    const int cit = lane & 15;
    const int rq = (lane >> 4) * 4;
#pragma unroll
    for (int rt = 0; rt < 2; ++rt)
#pragma unroll
        for (int n = 0; n < 8; ++n) {
            float bv = bias[n * 16 + cit];
            f32x4 v = acc[rt][n];
#pragma unroll
            for (int r = 0; r < 4; ++r) {
                int gr = row0 + wrow + rt * 16 + rq + r;
                if (gr < NN) {
                    float o = fmaxf(v[r] + bv, 0.f);
                    OutH[(size_t)gr * DF + n * 16 + cit] = f2h(o);
                }
            }
        }
}

// ---- layer 2 (128 packed cols): n 0-63 -> out = H@Ws2 + b2 (fp32);
//      n 64-127 -> g2 = H@Wn2 (fp16). W2 rows 0-63 = Ws2^T, 64-127 = Wn2^T.
__global__ __launch_bounds__(256) void gemm_l2_f16(
    const u16* __restrict__ H, const u16* __restrict__ W2,
    const float* __restrict__ b2, float* __restrict__ out, u16* __restrict__ g2) {
    __shared__ u16 As[128 * TS];
    __shared__ u16 Bs[64 * TS];
    const int tid = threadIdx.x;
    const int lane = tid & 63;
    const int wrow = (tid >> 6) * 32;
    const int row0 = blockIdx.x * 128;

    f32x4 acc[2][8];
#pragma unroll
    for (int rt = 0; rt < 2; ++rt)
#pragma unroll
        for (int n = 0; n < 8; ++n) acc[rt][n] = {0.f, 0.f, 0.f, 0.f};

    stage_a(As, H, row0, tid);
    stage_w(Bs, W2, 0, tid);
    __syncthreads();
    mfma4(As, Bs, wrow, lane, acc, 0);
    SW(W2, 64); mfma4(As, Bs, wrow, lane, acc, 4);

    const int cit = lane & 15;
    const int rq = (lane >> 4) * 4;
#pragma unroll
    for (int rt = 0; rt < 2; ++rt)
#pragma unroll
        for (int n = 0; n < 8; ++n) {
            f32x4 v = acc[rt][n];
            float bv = (n < 4) ? b2[n * 16 + cit] : 0.f;
#pragma unroll
            for (int r = 0; r < 4; ++r) {
                int gr = row0 + wrow + rt * 16 + rq + r;
                if (gr < NN) {
                    if (n < 4) out[(size_t)gr * 64 + n * 16 + cit] = v[r] + bv;
                    else g2[(size_t)gr * 64 + (n - 4) * 16 + cit] = f2h(v[r]);
                }
            }
        }
}

extern "C" void kernel_launch(void* const* d_in, const int* in_sizes, int n_in,
                              void* d_out, int out_size, void* d_ws, size_t ws_size,
                              hipStream_t stream) {
    const float* x   = (const float*)d_in[0];
    const int*   src = (const int*)d_in[1];
    const int*   dst = (const int*)d_in[2];
    const float* Ws0 = (const float*)d_in[3];
    const float* Wn0 = (const float*)d_in[4];
    const float* b0  = (const float*)d_in[5];
    const float* Ws1 = (const float*)d_in[6];
    const float* Wn1 = (const float*)d_in[7];
    const float* b1  = (const float*)d_in[8];
    const float* Ws2 = (const float*)d_in[9];
    const float* Wn2 = (const float*)d_in[10];
    const float* b2  = (const float*)d_in[11];
    float* out = (float*)d_out;

    // workspace (~66 MB):
    int* H       = (int*)d_ws;                 // NH (100096)
    int* O       = H + NH;                     // NH+1 (alloc 100352)
    int* rowptr  = O + 100352;                 // NN+1 (alloc 100352)
    int* col     = rowptr + 100352;            // NE
    uint32* ebuf = (uint32*)(col + NE);        // NE
    u16* WB      = (u16*)(ebuf + NE);          // 5 * 16384
    u16* W0s = WB, *W0n = WB + 16384, *W1s = WB + 2 * 16384, *W1n = WB + 3 * 16384;
    u16* W2  = WB + 4 * 16384;
    u16* P1 = WB + 5 * 16384;                  // fp16 x -> h1 -> h2 (in-place)
    u16* P3 = P1 + (size_t)NN * DF;            // fp16 mean0 -> mean1 -> g2

    const int gB = (NN + 127) / 128;           // 782

    // ---- CSR build: two-pass counting sort, wg-private write regions ----
    histA<<<NWA, 256, 0, stream>>>(dst, H);
    scanH<<<1, 1024, 0, stream>>>(H, O, rowptr);
    passA<<<NWA, 1024, 0, stream>>>(src, dst, O, ebuf);
    passB<<<NCB, 256, 0, stream>>>(ebuf, O, rowptr, col);

    // ---- weight prep (fp16, transposed; single launch) ----
    prep_all<<<320, 256, 0, stream>>>(Ws0, Wn0, Ws1, Wn1, Ws2, Wn2, WB);

    // ---- x -> fp16 ----
    cvt_f16<<<NN * DF / 4 / 256, 256, 0, stream>>>(x, (uint2*)P1);

    // ---- layer 0 ----
    gather_f16<<<NN / 4, 256, 0, stream>>>((const uint32*)P1, rowptr, col, (uint32*)P3);
    gemm_sage_f16<<<gB, 256, 0, stream>>>(P1, P3, W0s, W0n, b0, P1);

    // ---- layer 1 ----
    gather_f16<<<NN / 4, 256, 0, stream>>>((const uint32*)P1, rowptr, col, (uint32*)P3);
    gemm_sage_f16<<<gB, 256, 0, stream>>>(P1, P3, W1s, W1n, b1, P1);

    // ---- layer 2 (transform-then-aggregate) ----
    gemm_l2_f16<<<gB, 256, 0, stream>>>(P1, W2, b2, out, P3);
    gather_add_f16<<<NN / 4, 256, 0, stream>>>(P3, rowptr, col, out);
}

// Round 9
// 445.910 us; speedup vs baseline: 1.4117x; 1.4117x over previous
//
#include <hip/hip_runtime.h>

#define NN 100000
#define NE 1600000
#define DF 128
#define TS 136    // LDS row stride in u16: 272 B -> 2-way (free) bank aliasing on frag reads
#define NCB 391   // coarse buckets: dst>>8, 256 nodes each
#define NWA 256   // pass-A workgroups (wg-private regions scale with this)
#define SZA 6250  // edges per pass-A stripe (NE/NWA)
#define NH (NCB * NWA)  // 100096
#define CAPB 6144 // pass-B LDS seg capacity (mean 4092 edges/cb, +32 sigma)

typedef unsigned int uint32;
typedef unsigned short u16;
typedef _Float16 f16;
typedef f16 f16x8 __attribute__((ext_vector_type(8)));
typedef f16 f16x2 __attribute__((ext_vector_type(2)));
typedef float f32x4 __attribute__((ext_vector_type(4)));

// ---- fp16 helpers ----
__device__ __forceinline__ float2 up2(uint32 u) {
    union { uint32 u; f16x2 h; } v; v.u = u;
    return make_float2((float)v.h.x, (float)v.h.y);
}
__device__ __forceinline__ uint32 pk2(float a, float b) {
    union { f16x2 h; uint32 u; } v;
    v.h.x = (f16)a; v.h.y = (f16)b;
    return v.u;
}
__device__ __forceinline__ u16 f2h(float a) {
    union { f16 h; u16 u; } v; v.h = (f16)a; return v.u;
}
__device__ __forceinline__ float h2f(u16 a) {
    union { u16 u; f16 h; } v; v.u = a; return (float)v.h;
}

// ================= CSR build: two-pass counting sort =================
// Pass A partitions edges by coarse key (dst>>8) into ebuf with
// WORKGROUP-PRIVATE regions (no global atomics; minimal writeback
// amplification regardless of wg->XCD mapping).
// Scan is 3-level hierarchical (scanH at NH=100k was a 196us single-wg
// latency chain in round 8).
// Pass B sorts each coarse bucket fully in LDS -> coalesced col + rowptr.

__global__ __launch_bounds__(256) void histA(const int* __restrict__ dst,
                                             int* __restrict__ H) {
    __shared__ int lh[NCB];
    int w = blockIdx.x, t = threadIdx.x;
    for (int i = t; i < NCB; i += 256) lh[i] = 0;
    __syncthreads();
    int e0 = w * SZA, e1 = min(e0 + SZA, NE);
    for (int e = e0 + t; e < e1; e += 256) atomicAdd(&lh[dst[e] >> 8], 1);
    __syncthreads();
    for (int i = t; i < NCB; i += 256) H[i * NWA + w] = lh[i];
}

// level 1: per-coarse-bucket totals (391 wgs, tree reduce 256 counts)
__global__ __launch_bounds__(256) void sumCB(const int* __restrict__ H,
                                             int* __restrict__ CBT) {
    __shared__ int sm[256];
    int cb = blockIdx.x, t = threadIdx.x;
    sm[t] = H[cb * NWA + t];
    __syncthreads();
    for (int off = 128; off > 0; off >>= 1) {
        if (t < off) sm[t] += sm[t + off];
        __syncthreads();
    }
    if (t == 0) CBT[cb] = sm[0];
}

// level 2: exclusive scan of 391 totals (1 wg); writes sentinels
__global__ __launch_bounds__(512) void scanCB(const int* __restrict__ CBT,
                                              int* __restrict__ CBO,
                                              int* __restrict__ O,
                                              int* __restrict__ rowptr) {
    __shared__ int sm[512];
    int t = threadIdx.x;
    int v = (t < NCB) ? CBT[t] : 0;
    sm[t] = v;
    __syncthreads();
    for (int off = 1; off < 512; off <<= 1) {
        int x = (t >= off) ? sm[t - off] : 0;
        __syncthreads();
        sm[t] += x;
        __syncthreads();
    }
    if (t < NCB) CBO[t] = sm[t] - v;
    if (t == NCB - 1) {
        O[NH] = sm[t];       // = NE; passB's last bucket reads this
        rowptr[NN] = sm[t];  // = NE
    }
}

// level 3: per-cb exclusive scan of its 256 per-wg counts (391 wgs)
__global__ __launch_bounds__(256) void scanW(const int* __restrict__ H,
                                             const int* __restrict__ CBO,
                                             int* __restrict__ O) {
    __shared__ int sm[256];
    int cb = blockIdx.x, t = threadIdx.x;
    int v = H[cb * NWA + t];
    sm[t] = v;
    __syncthreads();
    for (int off = 1; off < 256; off <<= 1) {
        int x = (t >= off) ? sm[t - off] : 0;
        __syncthreads();
        sm[t] += x;
        __syncthreads();
    }
    O[cb * NWA + t] = CBO[cb] + sm[t] - v;
}

__global__ __launch_bounds__(1024) void passA(const int* __restrict__ src,
                                              const int* __restrict__ dst,
                                              const int* __restrict__ O,
                                              uint32* __restrict__ ebuf) {
    __shared__ int cur[NCB];
    int w = blockIdx.x, t = threadIdx.x;
    for (int i = t; i < NCB; i += 1024) cur[i] = O[i * NWA + w];
    __syncthreads();
    int e0 = w * SZA, e1 = min(e0 + SZA, NE);
    for (int e = e0 + t; e < e1; e += 1024) {
        int d = dst[e];
        int cb = d >> 8;
        int p = atomicAdd(&cur[cb], 1);  // LDS atomic; region private to this wg
        ebuf[p] = ((uint32)src[e] << 8) | (uint32)(d & 255);
    }
}

__global__ __launch_bounds__(256) void passB(const uint32* __restrict__ ebuf,
                                             const int* __restrict__ O,
                                             int* __restrict__ rowptr,
                                             int* __restrict__ col) {
    __shared__ int hist[256], start[256], cur[256];
    __shared__ int seg[CAPB];
    int cb = blockIdx.x, t = threadIdx.x;
    int base = O[cb * NWA], end = O[(cb + 1) * NWA];  // cb=NCB-1 reads O[NH]=NE
    int m = end - base;
    hist[t] = 0;
    __syncthreads();
    for (int i = t; i < m; i += 256) atomicAdd(&hist[ebuf[base + i] & 255], 1);
    __syncthreads();
    int v = hist[t];
    cur[t] = v;
    __syncthreads();
    for (int off = 1; off < 256; off <<= 1) {
        int x = (t >= off) ? cur[t - off] : 0;
        __syncthreads();
        cur[t] += x;
        __syncthreads();
    }
    start[t] = cur[t] - v;
    __syncthreads();
    int node = cb * 256 + t;
    if (node < NN) rowptr[node] = base + start[t];
    cur[t] = start[t];
    __syncthreads();
    if (m <= CAPB) {  // fast path: sort into LDS, stream out coalesced
        for (int i = t; i < m; i += 256) {
            uint32 u = ebuf[base + i];
            int p = atomicAdd(&cur[u & 255], 1);
            seg[p] = (int)(u >> 8);
        }
        __syncthreads();
        for (int i = t; i < m; i += 256) col[base + i] = seg[i];
    } else {  // correctness fallback
        for (int i = t; i < m; i += 256) {
            uint32 u = ebuf[base + i];
            int p = atomicAdd(&cur[u & 255], 1);
            col[base + p] = (int)(u >> 8);
        }
    }
}

// ======= weight prep, all 6 matrices in one launch: fp32 [k][n] -> fp16 [n][k]
__global__ void prep_all(const float* __restrict__ Ws0, const float* __restrict__ Wn0,
                         const float* __restrict__ Ws1, const float* __restrict__ Wn1,
                         const float* __restrict__ Ws2, const float* __restrict__ Wn2,
                         u16* __restrict__ WB) {
    int t = blockIdx.x * 256 + threadIdx.x;  // 0 .. 81919
    if (t < 65536) {
        int m = t >> 14;           // 0..3
        int local = t & 16383;
        int k = local >> 7, n = local & 127;
        const float* W = (m == 0) ? Ws0 : (m == 1) ? Wn0 : (m == 2) ? Ws1 : Wn1;
        WB[m * 16384 + n * 128 + k] = f2h(W[k * 128 + n]);
    } else {
        int local = t - 65536;     // 0 .. 16383
        int half = local >> 13;    // 0 = Ws2, 1 = Wn2
        int idx = local & 8191;
        int k = idx >> 6, n = idx & 63;
        const float* W = half ? Wn2 : Ws2;
        WB[4 * 16384 + (n + half * 64) * 128 + k] = f2h(W[k * 64 + n]);
    }
}

// ================= x -> fp16 =================
__global__ void cvt_f16(const float* __restrict__ x, uint2* __restrict__ xh) {
    int t = blockIdx.x * 256 + threadIdx.x;
    if (t < NN * DF / 4) {
        float4 v = ((const float4*)x)[t];
        uint2 o;
        o.x = pk2(v.x, v.y);
        o.y = pk2(v.z, v.w);
        xh[t] = o;
    }
}

// ================= gather mean, fp16 in/out, width 128 =================
__global__ __launch_bounds__(256) void gather_f16(const uint32* __restrict__ hb,
                                                  const int* __restrict__ rowptr,
                                                  const int* __restrict__ col,
                                                  uint32* __restrict__ mean) {
    int node = blockIdx.x * 4 + (threadIdx.x >> 6);
    int lane = threadIdx.x & 63;
    int s = rowptr[node], e = rowptr[node + 1];
    float sx = 0.f, sy = 0.f;
    int j = s;
    for (; j + 3 < e; j += 4) {
        int n0 = col[j], n1 = col[j + 1], n2 = col[j + 2], n3 = col[j + 3];
        uint32 u0 = hb[(size_t)n0 * 64 + lane];
        uint32 u1 = hb[(size_t)n1 * 64 + lane];
        uint32 u2 = hb[(size_t)n2 * 64 + lane];
        uint32 u3 = hb[(size_t)n3 * 64 + lane];
        float2 a = up2(u0), b = up2(u1), c = up2(u2), d = up2(u3);
        sx += a.x + b.x + c.x + d.x;
        sy += a.y + b.y + c.y + d.y;
    }
    for (; j < e; ++j) {
        float2 a = up2(hb[(size_t)col[j] * 64 + lane]);
        sx += a.x;
        sy += a.y;
    }
    float invd = 1.f / fmaxf((float)(e - s), 1.f);
    mean[(size_t)node * 64 + lane] = pk2(sx * invd, sy * invd);
}

// ================= gather mean-add, fp16 in, width 64, into fp32 out =========
__global__ __launch_bounds__(256) void gather_add_f16(const u16* __restrict__ gb,
                                                      const int* __restrict__ rowptr,
                                                      const int* __restrict__ col,
                                                      float* __restrict__ out) {
    int node = blockIdx.x * 4 + (threadIdx.x >> 6);
    int lane = threadIdx.x & 63;
    int s = rowptr[node], e = rowptr[node + 1];
    float acc = 0.f;
    int j = s;
    for (; j + 3 < e; j += 4) {
        int n0 = col[j], n1 = col[j + 1], n2 = col[j + 2], n3 = col[j + 3];
        acc += h2f(gb[(size_t)n0 * 64 + lane]) + h2f(gb[(size_t)n1 * 64 + lane]) +
               h2f(gb[(size_t)n2 * 64 + lane]) + h2f(gb[(size_t)n3 * 64 + lane]);
    }
    for (; j < e; ++j) acc += h2f(gb[(size_t)col[j] * 64 + lane]);
    float invd = 1.f / fmaxf((float)(e - s), 1.f);
    out[(size_t)node * 64 + lane] += acc * invd;
}

// ================= MFMA GEMM building blocks (fp16) ======
__device__ __forceinline__ void stage_a(u16* sm, const u16* g, int row0, int tid) {
#pragma unroll
    for (int i = 0; i < 8; ++i) {
        int idx = i * 256 + tid;
        int r = idx >> 4, c = (idx & 15) * 8;
        uint4 v = make_uint4(0, 0, 0, 0);
        int gr = row0 + r;
        if (gr < NN) v = *(const uint4*)(g + (size_t)gr * DF + c);
        *(uint4*)(sm + r * TS + c) = v;
    }
}

__device__ __forceinline__ void stage_w(u16* sm, const u16* wt, int nbase, int tid) {
#pragma unroll
    for (int i = 0; i < 4; ++i) {
        int idx = i * 256 + tid;
        int r = idx >> 4, c = (idx & 15) * 8;
        *(uint4*)(sm + r * TS + c) = *(const uint4*)(wt + (size_t)(nbase + r) * 128 + c);
    }
}

__device__ __forceinline__ f16x8 frag(const u16* sm, int row, int lane, int kc) {
    return *(const f16x8*)(sm + (row + (lane & 15)) * TS + kc * 32 + (lane >> 4) * 8);
}

__device__ __forceinline__ void mfma4(const u16* As, const u16* Bs, int wrow, int lane,
                                      f32x4 acc[2][8], int ab) {
    f16x8 a[2][4];
#pragma unroll
    for (int rt = 0; rt < 2; ++rt)
#pragma unroll
        for (int kc = 0; kc < 4; ++kc) a[rt][kc] = frag(As, wrow + rt * 16, lane, kc);
#pragma unroll
    for (int n = 0; n < 4; ++n) {
#pragma unroll
        for (int kc = 0; kc < 4; ++kc) {
            f16x8 b = frag(Bs, n * 16, lane, kc);
            acc[0][ab + n] = __builtin_amdgcn_mfma_f32_16x16x32_f16(a[0][kc], b, acc[0][ab + n], 0, 0, 0);
            acc[1][ab + n] = __builtin_amdgcn_mfma_f32_16x16x32_f16(a[1][kc], b, acc[1][ab + n], 0, 0, 0);
        }
    }
}

#define SW(WT, NB) { __syncthreads(); stage_w(Bs, WT, NB, tid); __syncthreads(); }

// ---- fused SAGE layer (DO=128): OutH = fp16(relu(H@Ws + M@Wn + b)), in-place safe
__global__ __launch_bounds__(256) void gemm_sage_f16(
    const u16* H, const u16* M,
    const u16* __restrict__ Ws, const u16* __restrict__ Wn,
    const float* __restrict__ bias, u16* OutH) {
    __shared__ u16 As[128 * TS];
    __shared__ u16 Bs[64 * TS];
    const int tid = threadIdx.x;
    const int lane = tid & 63;
    const int wrow = (tid >> 6) * 32;
    const int row0 = blockIdx.x * 128;

    f32x4 acc[2][8];
#pragma unroll
    for (int rt = 0; rt < 2; ++rt)
#pragma unroll
        for (int n = 0; n < 8; ++n) acc[rt][n] = {0.f, 0.f, 0.f, 0.f};

    stage_a(As, H, row0, tid);
    stage_w(Bs, Ws, 0, tid);
    __syncthreads();
    mfma4(As, Bs, wrow, lane, acc, 0);
    SW(Ws, 64); mfma4(As, Bs, wrow, lane, acc, 4);
    __syncthreads();
    stage_a(As, M, row0, tid);
    stage_w(Bs, Wn, 0, tid);
    __syncthreads();
    mfma4(As, Bs, wrow, lane, acc, 0);
    SW(Wn, 64); mfma4(As, Bs, wrow, lane, acc, 4);

    const int cit = lane & 15;
    const int rq = (lane >> 4) * 4;
#pragma unroll
    for (int rt = 0; rt < 2; ++rt)
#pragma unroll
        for (int n = 0; n < 8; ++n) {
            float bv = bias[n * 16 + cit];
            f32x4 v = acc[rt][n];
#pragma unroll
            for (int r = 0; r < 4; ++r) {
                int gr = row0 + wrow + rt * 16 + rq + r;
                if (gr < NN) {
                    float o = fmaxf(v[r] + bv, 0.f);
                    OutH[(size_t)gr * DF + n * 16 + cit] = f2h(o);
                }
            }
        }
}

// ---- layer 2 (128 packed cols): n 0-63 -> out = H@Ws2 + b2 (fp32);
//      n 64-127 -> g2 = H@Wn2 (fp16). W2 rows 0-63 = Ws2^T, 64-127 = Wn2^T.
__global__ __launch_bounds__(256) void gemm_l2_f16(
    const u16* __restrict__ H, const u16* __restrict__ W2,
    const float* __restrict__ b2, float* __restrict__ out, u16* __restrict__ g2) {
    __shared__ u16 As[128 * TS];
    __shared__ u16 Bs[64 * TS];
    const int tid = threadIdx.x;
    const int lane = tid & 63;
    const int wrow = (tid >> 6) * 32;
    const int row0 = blockIdx.x * 128;

    f32x4 acc[2][8];
#pragma unroll
    for (int rt = 0; rt < 2; ++rt)
#pragma unroll
        for (int n = 0; n < 8; ++n) acc[rt][n] = {0.f, 0.f, 0.f, 0.f};

    stage_a(As, H, row0, tid);
    stage_w(Bs, W2, 0, tid);
    __syncthreads();
    mfma4(As, Bs, wrow, lane, acc, 0);
    SW(W2, 64); mfma4(As, Bs, wrow, lane, acc, 4);

    const int cit = lane & 15;
    const int rq = (lane >> 4) * 4;
#pragma unroll
    for (int rt = 0; rt < 2; ++rt)
#pragma unroll
        for (int n = 0; n < 8; ++n) {
            f32x4 v = acc[rt][n];
            float bv = (n < 4) ? b2[n * 16 + cit] : 0.f;
#pragma unroll
            for (int r = 0; r < 4; ++r) {
                int gr = row0 + wrow + rt * 16 + rq + r;
                if (gr < NN) {
                    if (n < 4) out[(size_t)gr * 64 + n * 16 + cit] = v[r] + bv;
                    else g2[(size_t)gr * 64 + (n - 4) * 16 + cit] = f2h(v[r]);
                }
            }
        }
}

extern "C" void kernel_launch(void* const* d_in, const int* in_sizes, int n_in,
                              void* d_out, int out_size, void* d_ws, size_t ws_size,
                              hipStream_t stream) {
    const float* x   = (const float*)d_in[0];
    const int*   src = (const int*)d_in[1];
    const int*   dst = (const int*)d_in[2];
    const float* Ws0 = (const float*)d_in[3];
    const float* Wn0 = (const float*)d_in[4];
    const float* b0  = (const float*)d_in[5];
    const float* Ws1 = (const float*)d_in[6];
    const float* Wn1 = (const float*)d_in[7];
    const float* b1  = (const float*)d_in[8];
    const float* Ws2 = (const float*)d_in[9];
    const float* Wn2 = (const float*)d_in[10];
    const float* b2  = (const float*)d_in[11];
    float* out = (float*)d_out;

    // workspace (~66 MB):
    int* H       = (int*)d_ws;                 // NH (100096)
    int* O       = H + NH;                     // NH+1 (alloc 100352)
    int* CBT     = O + 100352;                 // NCB (alloc 512)
    int* CBO     = CBT + 512;                  // NCB (alloc 512)
    int* rowptr  = CBO + 512;                  // NN+1 (alloc 100352)
    int* col     = rowptr + 100352;            // NE
    uint32* ebuf = (uint32*)(col + NE);        // NE
    u16* WB      = (u16*)(ebuf + NE);          // 5 * 16384
    u16* W0s = WB, *W0n = WB + 16384, *W1s = WB + 2 * 16384, *W1n = WB + 3 * 16384;
    u16* W2  = WB + 4 * 16384;
    u16* P1 = WB + 5 * 16384;                  // fp16 x -> h1 -> h2 (in-place)
    u16* P3 = P1 + (size_t)NN * DF;            // fp16 mean0 -> mean1 -> g2

    const int gB = (NN + 127) / 128;           // 782

    // ---- CSR build: two-pass counting sort, hierarchical scan ----
    histA<<<NWA, 256, 0, stream>>>(dst, H);
    sumCB<<<NCB, 256, 0, stream>>>(H, CBT);
    scanCB<<<1, 512, 0, stream>>>(CBT, CBO, O, rowptr);
    scanW<<<NCB, 256, 0, stream>>>(H, CBO, O);
    passA<<<NWA, 1024, 0, stream>>>(src, dst, O, ebuf);
    passB<<<NCB, 256, 0, stream>>>(ebuf, O, rowptr, col);

    // ---- weight prep (fp16, transposed; single launch) ----
    prep_all<<<320, 256, 0, stream>>>(Ws0, Wn0, Ws1, Wn1, Ws2, Wn2, WB);

    // ---- x -> fp16 ----
    cvt_f16<<<NN * DF / 4 / 256, 256, 0, stream>>>(x, (uint2*)P1);

    // ---- layer 0 ----
    gather_f16<<<NN / 4, 256, 0, stream>>>((const uint32*)P1, rowptr, col, (uint32*)P3);
    gemm_sage_f16<<<gB, 256, 0, stream>>>(P1, P3, W0s, W0n, b0, P1);

    // ---- layer 1 ----
    gather_f16<<<NN / 4, 256, 0, stream>>>((const uint32*)P1, rowptr, col, (uint32*)P3);
    gemm_sage_f16<<<gB, 256, 0, stream>>>(P1, P3, W1s, W1n, b1, P1);

    // ---- layer 2 (transform-then-aggregate) ----
    gemm_l2_f16<<<gB, 256, 0, stream>>>(P1, W2, b2, out, P3);
    gather_add_f16<<<NN / 4, 256, 0, stream>>>(P3, rowptr, col, out);
}